// Round 10
// baseline (156.944 us; speedup 1.0000x reference)
//
#include <hip/hip_runtime.h>

typedef __attribute__((ext_vector_type(8))) short s16x8;
typedef __attribute__((ext_vector_type(4))) float f32x4;

#define B_  4
#define C_  256
#define N_  4096
#define NT  32
#define NPJ 64   // j-chunks in k_sumexp
#define EPSN 2.220446049250313e-16f

static __device__ __forceinline__ unsigned short f2bf(float f) {
  unsigned int u = __float_as_uint(f);
  u += 0x7fffu + ((u >> 16) & 1u);   // round-to-nearest-even
  return (unsigned short)(u >> 16);
}
static __device__ __forceinline__ float bf2f(unsigned short s) {
  return __uint_as_float(((unsigned int)s) << 16);
}

static __device__ __forceinline__ void gload16(const void* gp, void* lp) {
  __builtin_amdgcn_global_load_lds(
      (const __attribute__((address_space(1))) unsigned int*)gp,
      (__attribute__((address_space(3))) unsigned int*)lp, 16, 0, 0);
}

// ---------- mean of Y over spatial dims: mu[b*C+c] ----------
__global__ void k_mu(const float* __restrict__ Y, float* __restrict__ mu) {
  const int bc = blockIdx.x;      // B_*C_ blocks
  const int t  = threadIdx.x;     // 256
  const float4* p4 = (const float4*)(Y + (size_t)bc * N_);
  float s = 0.f;
#pragma unroll
  for (int i = 0; i < 4; ++i) {
    float4 v = p4[i * 256 + t];
    s += (v.x + v.y) + (v.z + v.w);
  }
#pragma unroll
  for (int off = 32; off; off >>= 1) s += __shfl_down(s, off);
  __shared__ float sw_[4];
  if ((t & 63) == 0) sw_[t >> 6] = s;
  __syncthreads();
  if (t == 0) mu[bc] = (sw_[0] + sw_[1] + sw_[2] + sw_[3]) * (1.0f / (float)N_);
}

// ---------- center + L2-normalize over channels, emit bf16 [b][n][c] ----------
__global__ void __launch_bounds__(256) k_norm(
    const float* __restrict__ X, const float* __restrict__ Y,
    const float* __restrict__ mu,
    unsigned short* __restrict__ Xn, unsigned short* __restrict__ Yn) {
  const int b  = blockIdx.x >> 7;          // grid = B_*128
  const int n0 = (blockIdx.x & 127) << 5;  // 32 spatial positions per block
  const int t  = threadIdx.x;
  const int tn = t & 31;
  const int tc = t >> 5;                   // 0..7 : c-group of 32
  const int n  = n0 + tn;

  __shared__ float  smu[C_];
  __shared__ float2 sred[8][32];
  __shared__ float2 sinv2[32];

  smu[t] = mu[b * C_ + t];
  __syncthreads();

  const float* Xb = X + (size_t)b * C_ * N_;
  const float* Yb = Y + (size_t)b * C_ * N_;

  float xv[32], yv[32];
  float ssx = 0.f, ssy = 0.f;
#pragma unroll
  for (int i = 0; i < 32; ++i) {
    const int c = tc * 32 + i;
    const float m = smu[c];
    const float x = Xb[(size_t)c * N_ + n] - m;
    const float y = Yb[(size_t)c * N_ + n] - m;
    xv[i] = x; yv[i] = y;
    ssx += x * x; ssy += y * y;
  }
  sred[tc][tn] = make_float2(ssx, ssy);
  __syncthreads();
  if (tc == 0) {
    float sx = 0.f, sy = 0.f;
#pragma unroll
    for (int i = 0; i < 8; ++i) { float2 v = sred[i][tn]; sx += v.x; sy += v.y; }
    sinv2[tn] = make_float2(1.0f / (sqrtf(sx) + EPSN), 1.0f / (sqrtf(sy) + EPSN));
  }
  __syncthreads();
  const float ivx = sinv2[tn].x, ivy = sinv2[tn].y;

  unsigned short* Xr = Xn + (size_t)(b * N_ + n) * C_ + tc * 32;
  unsigned short* Yr = Yn + (size_t)(b * N_ + n) * C_ + tc * 32;
#pragma unroll
  for (int c0 = 0; c0 < 4; ++c0) {
    s16x8 vx, vy;
#pragma unroll
    for (int i = 0; i < 8; ++i) {
      vx[i] = (short)f2bf(xv[c0 * 8 + i] * ivx);
      vy[i] = (short)f2bf(yv[c0 * 8 + i] * ivy);
    }
    *(s16x8*)(Xr + c0 * 8) = vx;
    *(s16x8*)(Yr + c0 * 8) = vy;
  }
}

// ---------- 128x128 bf16 MFMA GEMM tile (round-3 K-loop, coalesced sT epilogue) ----------
// PASS 0: row-min only (fallback)   PASS 1: row-sum-exp (fallback)
// PASS 2: row-min partials + materialize s^T bf16 via LDS-transposed coalesced stores
template <int PASS>
__global__ void __launch_bounds__(256)
k_gemm(const unsigned short* __restrict__ Xn, const unsigned short* __restrict__ Yn,
       float* __restrict__ pout, const float* __restrict__ minf,
       unsigned short* __restrict__ sT) {
  const int bid = blockIdx.x;          // B_*NT*NT
  const int b  = bid >> 10;
  const int it = (bid >> 5) & 31;
  const int jt = bid & 31;
  const int t    = threadIdx.x;
  const int lane = t & 63;
  const int wave = t >> 6;
  const int wr = wave >> 1;
  const int wc = wave & 1;

  // one carve: K-loop uses [0,16384) shorts as Al|Bl; PASS-2 epilogue reuses
  // the whole buffer as a [128][136] transpose tile (272B stride, 16B-aligned rows)
  __shared__ unsigned short smem[128 * 136];   // 34816 B
  __shared__ float lred[2][128];
  unsigned short* Al = smem;
  unsigned short* Bl = smem + 128 * 64;

  const unsigned short* gX = Xn + ((size_t)b * N_ + (size_t)it * 128) * C_;
  const unsigned short* gY = Yn + ((size_t)b * N_ + (size_t)jt * 128) * C_;

  f32x4 acc[4][4];
  const f32x4 fz = {0.f, 0.f, 0.f, 0.f};
#pragma unroll
  for (int m = 0; m < 4; ++m)
#pragma unroll
    for (int n = 0; n < 4; ++n) acc[m][n] = fz;

  const int srow = t >> 3;   // 0..31 (row within 32-row issue)
  const int sch0 = t & 7;    // 16B chunk within 128B row

  for (int kk = 0; kk < 4; ++kk) {
#pragma unroll
    for (int is = 0; is < 4; ++is) {
      const int row = is * 32 + srow;
      const int ch  = sch0 ^ (row & 7);                 // inverse-swizzled SOURCE
      const size_t goff = (size_t)row * C_ + kk * 64 + ch * 8;
      char* la = (char*)Al + is * 4096 + wave * 1024;   // wave-uniform linear dest
      char* lb = (char*)Bl + is * 4096 + wave * 1024;
      gload16(gX + goff, la);
      gload16(gY + goff, lb);
    }
    __syncthreads();
#pragma unroll
    for (int ks = 0; ks < 2; ++ks) {
      s16x8 af[4], bf[4];
#pragma unroll
      for (int m = 0; m < 4; ++m) {
        const int row = wr * 64 + m * 16 + (lane & 15);
        const int ch  = (ks * 4 + (lane >> 4)) ^ (row & 7);  // swizzled READ
        af[m] = *(const s16x8*)((const char*)Al + row * 128 + ch * 16);
      }
#pragma unroll
      for (int n = 0; n < 4; ++n) {
        const int row = wc * 64 + n * 16 + (lane & 15);
        const int ch  = (ks * 4 + (lane >> 4)) ^ (row & 7);
        bf[n] = *(const s16x8*)((const char*)Bl + row * 128 + ch * 16);
      }
#pragma unroll
      for (int m = 0; m < 4; ++m)
#pragma unroll
        for (int n = 0; n < 4; ++n)
          acc[m][n] = __builtin_amdgcn_mfma_f32_16x16x32_bf16(af[m], bf[n], acc[m][n], 0, 0, 0);
    }
    __syncthreads();
  }

  const int g = lane >> 4;

  // per-row (over this block's 128 cols) min or sum(exp) into lred
#pragma unroll
  for (int m = 0; m < 4; ++m) {
#pragma unroll
    for (int j = 0; j < 4; ++j) {
      const int r = wr * 64 + m * 16 + g * 4 + j;   // local output row
      float v;
      if (PASS != 1) {
        v = 1e30f;
#pragma unroll
        for (int n = 0; n < 4; ++n) {
          float d = fmaxf(1.0f - acc[m][n][j], 0.0f);
          v = fminf(v, d);
        }
#pragma unroll
        for (int off = 1; off < 16; off <<= 1) v = fminf(v, __shfl_xor(v, off));
      } else {
        const float mv  = minf[(size_t)b * N_ + it * 128 + r];
        const float inv = 10.0f / (mv + 1e-5f);
        v = 0.f;
#pragma unroll
        for (int n = 0; n < 4; ++n) {
          float d = fmaxf(1.0f - acc[m][n][j], 0.0f);
          v += __expf(10.0f - d * inv);
        }
#pragma unroll
        for (int off = 1; off < 16; off <<= 1) v += __shfl_xor(v, off);
      }
      if ((lane & 15) == 0) lred[wc][r] = v;
    }
  }

  if (PASS == 2) {
    // deposit acc fragments into the transpose tile: smem[c_local][r_local]
    // (K-loop done with smem; the barrier below also covers lred)
    __syncthreads();
    if (t < 128) {
      const float a = lred[0][t], c = lred[1][t];
      pout[(size_t)jt * (B_ * N_) + b * N_ + it * 128 + t] = fminf(a, c);
    }
#pragma unroll
    for (int m = 0; m < 4; ++m) {
#pragma unroll
      for (int n = 0; n < 4; ++n) {
        const int cl = wc * 64 + n * 16 + (lane & 15);   // local Y (col) index
        const int rl = wr * 64 + m * 16 + g * 4;         // local X (row) index
        ushort4 pk;
        pk.x = f2bf(acc[m][n][0]); pk.y = f2bf(acc[m][n][1]);
        pk.z = f2bf(acc[m][n][2]); pk.w = f2bf(acc[m][n][3]);
        *(ushort4*)(smem + cl * 136 + rl) = pk;          // 8B aligned (rl%4==0)
      }
    }
    __syncthreads();
    // coalesced store: thread t -> c = t>>1, half = t&1; 128B contiguous per lane
    {
      const int cl = t >> 1;
      const int hf = t & 1;
      unsigned short* gdst =
          sT + ((size_t)b * N_ + (size_t)jt * 128 + cl) * N_ + it * 128 + hf * 64;
      const unsigned short* lsrc = smem + cl * 136 + hf * 64;
#pragma unroll
      for (int i = 0; i < 8; ++i)
        *(s16x8*)(gdst + i * 8) = *(const s16x8*)(lsrc + i * 8);  // 16B, aligned
    }
    return;
  }

  // fallback epilogue (PASS 0 / PASS 1)
  __syncthreads();
  if (t < 128) {
    const float a = lred[0][t], c = lred[1][t];
    pout[(size_t)jt * (B_ * N_) + b * N_ + it * 128 + t] = (PASS == 1) ? (a + c) : fminf(a, c);
  }
}

// ---------- fold 32 j-tile partial mins ----------
__global__ void k_minred(const float* __restrict__ pmin, float* __restrict__ minf) {
  const int r = blockIdx.x * 256 + threadIdx.x;   // 16384 rows
  float v = 1e30f;
#pragma unroll 4
  for (int i = 0; i < 32; ++i) v = fminf(v, pmin[(size_t)i * (B_ * N_) + r]);
  minf[r] = v;
}

// ---------- streaming sum-exp over materialized s^T ----------
// grid = B_*2*NPJ ; each block: 2048 rows (8/thread) x (4096/NPJ) cols
__global__ void __launch_bounds__(256) k_sumexp(
    const unsigned short* __restrict__ sT, const float* __restrict__ minf,
    float* __restrict__ psum) {
  const int bid = blockIdx.x;
  const int b  = bid / (2 * NPJ);
  const int rh = (bid / NPJ) & 1;
  const int jc = bid % NPJ;
  const int t  = threadIdx.x;
  const int r0 = rh * 2048 + t * 8;
  const int CC = N_ / NPJ;  // 64 cols per block

  const unsigned short* base = sT + ((size_t)b * N_ + (size_t)jc * CC) * N_ + r0;

  float alpha[8], acc8[8];
#pragma unroll
  for (int i = 0; i < 8; ++i) {
    const float m = minf[b * N_ + r0 + i];
    alpha[i] = 10.0f / (m + 1e-5f);
    acc8[i] = 0.f;
  }

  for (int c = 0; c < CC; c += 4) {
    s16x8 v0 = *(const s16x8*)(base + (size_t)(c    ) * N_);
    s16x8 v1 = *(const s16x8*)(base + (size_t)(c + 1) * N_);
    s16x8 v2 = *(const s16x8*)(base + (size_t)(c + 2) * N_);
    s16x8 v3 = *(const s16x8*)(base + (size_t)(c + 3) * N_);
#pragma unroll
    for (int i = 0; i < 8; ++i) {
      float d0 = fmaxf(1.0f - bf2f((unsigned short)v0[i]), 0.0f);
      float d1 = fmaxf(1.0f - bf2f((unsigned short)v1[i]), 0.0f);
      float d2 = fmaxf(1.0f - bf2f((unsigned short)v2[i]), 0.0f);
      float d3 = fmaxf(1.0f - bf2f((unsigned short)v3[i]), 0.0f);
      acc8[i] += __expf(10.0f - d0 * alpha[i]) + __expf(10.0f - d1 * alpha[i]);
      acc8[i] += __expf(10.0f - d2 * alpha[i]) + __expf(10.0f - d3 * alpha[i]);
    }
  }
  float* out = psum + (size_t)jc * (B_ * N_) + b * N_ + r0;
#pragma unroll
  for (int i = 0; i < 8; ++i) out[i] = acc8[i];
}

// ---------- per-row contribution: exp((1-m/(m+1e-5))/h) / S ----------
template <int NP>
__global__ void k_contrib(const float* __restrict__ psum, const float* __restrict__ minf,
                          float* __restrict__ contrib) {
  const int r = blockIdx.x * 256 + threadIdx.x;
  float s = 0.f;
#pragma unroll 4
  for (int i = 0; i < NP; ++i) s += psum[(size_t)i * (B_ * N_) + r];
  const float m = minf[r];
  const float num = __expf(10.0f - 10.0f * m / (m + 1e-5f));
  contrib[r] = num / s;
}

// ---------- final loss ----------
__global__ void k_loss(const float* __restrict__ contrib, float* __restrict__ out) {
  const int t = threadIdx.x;    // 256
  __shared__ float sw_[4];
  float loss = 0.f;
  for (int b = 0; b < B_; ++b) {
    float s = 0.f;
    for (int i = t; i < N_; i += 256) s += contrib[b * N_ + i];
#pragma unroll
    for (int off = 32; off; off >>= 1) s += __shfl_down(s, off);
    if ((t & 63) == 0) sw_[t >> 6] = s;
    __syncthreads();
    if (t == 0) {
      const float cx = (sw_[0] + sw_[1] + sw_[2] + sw_[3]) * (1.0f / (float)N_);
      loss += -logf(cx);
    }
    __syncthreads();
  }
  if (t == 0) out[0] = loss * (1.0f / (float)B_);
}

extern "C" void kernel_launch(void* const* d_in, const int* in_sizes, int n_in,
                              void* d_out, int out_size, void* d_ws, size_t ws_size,
                              hipStream_t stream) {
  const float* X = (const float*)d_in[0];
  const float* Y = (const float*)d_in[1];
  float* out = (float*)d_out;

  char* w = (char*)d_ws;
  size_t off = 0;
  float*          mu   = (float*)(w + off);  off += 4096;
  unsigned short* Xn   = (unsigned short*)(w + off);  off += 8388608;
  unsigned short* Yn   = (unsigned short*)(w + off);  off += 8388608;
  float*          pmin = (float*)(w + off);  off += 2097152;              // 32 partials
  float*          psum = (float*)(w + off);  off += (size_t)NPJ * B_ * N_ * 4;  // 4 MB
  float*          minf = (float*)(w + off);  off += 65536;
  float*          ctr  = (float*)(w + off);  off += 65536;
  unsigned short* sT   = (unsigned short*)(w + off);
  const size_t need = off + (size_t)B_ * N_ * N_ * 2;   // ~150 MB

  k_mu   <<<B_ * C_,  256, 0, stream>>>(Y, mu);
  k_norm <<<B_ * 128, 256, 0, stream>>>(X, Y, mu, Xn, Yn);

  if (ws_size >= need) {
    // fast path: one GEMM materializes s^T (coalesced) + row-min partials
    k_gemm<2><<<B_ * NT * NT, 256, 0, stream>>>(Xn, Yn, pmin, nullptr, sT);
    k_minred<<<B_ * N_ / 256, 256, 0, stream>>>(pmin, minf);
    k_sumexp<<<B_ * 2 * NPJ,  256, 0, stream>>>(sT, minf, psum);
    k_contrib<NPJ><<<B_ * N_ / 256, 256, 0, stream>>>(psum, minf, ctr);
  } else {
    // fallback: two GEMM passes
    k_gemm<0><<<B_ * NT * NT, 256, 0, stream>>>(Xn, Yn, pmin, nullptr, nullptr);
    k_minred<<<B_ * N_ / 256, 256, 0, stream>>>(pmin, minf);
    k_gemm<1><<<B_ * NT * NT, 256, 0, stream>>>(Xn, Yn, psum, minf, nullptr);
    k_contrib<32><<<B_ * N_ / 256, 256, 0, stream>>>(psum, minf, ctr);
  }
  k_loss <<<1, 256, 0, stream>>>(ctr, out);

  (void)in_sizes; (void)n_in; (void)out_size; (void)ws_size;
}

// Round 11
// 138.588 us; speedup vs baseline: 1.1325x; 1.1325x over previous
//
#include <hip/hip_runtime.h>

typedef __attribute__((ext_vector_type(8))) short s16x8;
typedef __attribute__((ext_vector_type(4))) float f32x4;
typedef __attribute__((ext_vector_type(2))) float f32x2;

#define B_  4
#define C_  256
#define N_  4096
#define NT  32
#define NPJ 64   // j-chunks in k_sumexp
#define EPSN 2.220446049250313e-16f

static __device__ __forceinline__ unsigned short f2bf(float f) {
  unsigned int u = __float_as_uint(f);
  u += 0x7fffu + ((u >> 16) & 1u);   // round-to-nearest-even
  return (unsigned short)(u >> 16);
}

static __device__ __forceinline__ void gload16(const void* gp, void* lp) {
  __builtin_amdgcn_global_load_lds(
      (const __attribute__((address_space(1))) unsigned int*)gp,
      (__attribute__((address_space(3))) unsigned int*)lp, 16, 0, 0);
}

// ---------- mean of Y over spatial dims: mu[b*C+c] ----------
__global__ void k_mu(const float* __restrict__ Y, float* __restrict__ mu) {
  const int bc = blockIdx.x;      // B_*C_ blocks
  const int t  = threadIdx.x;     // 256
  const float4* p4 = (const float4*)(Y + (size_t)bc * N_);
  float s = 0.f;
#pragma unroll
  for (int i = 0; i < 4; ++i) {
    float4 v = p4[i * 256 + t];
    s += (v.x + v.y) + (v.z + v.w);
  }
#pragma unroll
  for (int off = 32; off; off >>= 1) s += __shfl_down(s, off);
  __shared__ float sw_[4];
  if ((t & 63) == 0) sw_[t >> 6] = s;
  __syncthreads();
  if (t == 0) mu[bc] = (sw_[0] + sw_[1] + sw_[2] + sw_[3]) * (1.0f / (float)N_);
}

// ---------- center + L2-normalize over channels, emit bf16 [b][n][c] ----------
__global__ void __launch_bounds__(256) k_norm(
    const float* __restrict__ X, const float* __restrict__ Y,
    const float* __restrict__ mu,
    unsigned short* __restrict__ Xn, unsigned short* __restrict__ Yn) {
  const int b  = blockIdx.x >> 7;          // grid = B_*128
  const int n0 = (blockIdx.x & 127) << 5;  // 32 spatial positions per block
  const int t  = threadIdx.x;
  const int tn = t & 31;
  const int tc = t >> 5;                   // 0..7 : c-group of 32
  const int n  = n0 + tn;

  __shared__ float  smu[C_];
  __shared__ float2 sred[8][32];
  __shared__ float2 sinv2[32];

  smu[t] = mu[b * C_ + t];
  __syncthreads();

  const float* Xb = X + (size_t)b * C_ * N_;
  const float* Yb = Y + (size_t)b * C_ * N_;

  float xv[32], yv[32];
  float ssx = 0.f, ssy = 0.f;
#pragma unroll
  for (int i = 0; i < 32; ++i) {
    const int c = tc * 32 + i;
    const float m = smu[c];
    const float x = Xb[(size_t)c * N_ + n] - m;
    const float y = Yb[(size_t)c * N_ + n] - m;
    xv[i] = x; yv[i] = y;
    ssx += x * x; ssy += y * y;
  }
  sred[tc][tn] = make_float2(ssx, ssy);
  __syncthreads();
  if (tc == 0) {
    float sx = 0.f, sy = 0.f;
#pragma unroll
    for (int i = 0; i < 8; ++i) { float2 v = sred[i][tn]; sx += v.x; sy += v.y; }
    sinv2[tn] = make_float2(1.0f / (sqrtf(sx) + EPSN), 1.0f / (sqrtf(sy) + EPSN));
  }
  __syncthreads();
  const float ivx = sinv2[tn].x, ivy = sinv2[tn].y;

  unsigned short* Xr = Xn + (size_t)(b * N_ + n) * C_ + tc * 32;
  unsigned short* Yr = Yn + (size_t)(b * N_ + n) * C_ + tc * 32;
#pragma unroll
  for (int c0 = 0; c0 < 4; ++c0) {
    s16x8 vx, vy;
#pragma unroll
    for (int i = 0; i < 8; ++i) {
      vx[i] = (short)f2bf(xv[c0 * 8 + i] * ivx);
      vy[i] = (short)f2bf(yv[c0 * 8 + i] * ivy);
    }
    *(s16x8*)(Xr + c0 * 8) = vx;
    *(s16x8*)(Yr + c0 * 8) = vy;
  }
}

// ---------- 128x128 bf16 MFMA GEMM tile (round-3 structure, fp8 sT) ----------
// PASS 0: row-min only (fallback)   PASS 1: row-sum-exp (fallback)
// PASS 2: row-min partials + materialize s^T as fp8 e4m3 (fast path)
template <int PASS>
__global__ void __launch_bounds__(256)
k_gemm(const unsigned short* __restrict__ Xn, const unsigned short* __restrict__ Yn,
       float* __restrict__ pout, const float* __restrict__ minf,
       unsigned char* __restrict__ sT) {
  const int bid = blockIdx.x;          // B_*NT*NT
  const int b  = bid >> 10;
  const int it = (bid >> 5) & 31;
  const int jt = bid & 31;
  const int t    = threadIdx.x;
  const int lane = t & 63;
  const int wave = t >> 6;
  const int wr = wave >> 1;
  const int wc = wave & 1;

  __shared__ unsigned short Al[128 * 64];
  __shared__ unsigned short Bl[128 * 64];
  __shared__ float lred[2][128];

  const unsigned short* gX = Xn + ((size_t)b * N_ + (size_t)it * 128) * C_;
  const unsigned short* gY = Yn + ((size_t)b * N_ + (size_t)jt * 128) * C_;

  f32x4 acc[4][4];
  const f32x4 fz = {0.f, 0.f, 0.f, 0.f};
#pragma unroll
  for (int m = 0; m < 4; ++m)
#pragma unroll
    for (int n = 0; n < 4; ++n) acc[m][n] = fz;

  const int srow = t >> 3;   // 0..31 (row within 32-row issue)
  const int sch0 = t & 7;    // 16B chunk within 128B row

  for (int kk = 0; kk < 4; ++kk) {
#pragma unroll
    for (int is = 0; is < 4; ++is) {
      const int row = is * 32 + srow;
      const int ch  = sch0 ^ (row & 7);                 // inverse-swizzled SOURCE
      const size_t goff = (size_t)row * C_ + kk * 64 + ch * 8;
      char* la = (char*)Al + is * 4096 + wave * 1024;   // wave-uniform linear dest
      char* lb = (char*)Bl + is * 4096 + wave * 1024;
      gload16(gX + goff, la);
      gload16(gY + goff, lb);
    }
    __syncthreads();
#pragma unroll
    for (int ks = 0; ks < 2; ++ks) {
      s16x8 af[4], bf[4];
#pragma unroll
      for (int m = 0; m < 4; ++m) {
        const int row = wr * 64 + m * 16 + (lane & 15);
        const int ch  = (ks * 4 + (lane >> 4)) ^ (row & 7);  // swizzled READ
        af[m] = *(const s16x8*)((const char*)Al + row * 128 + ch * 16);
      }
#pragma unroll
      for (int n = 0; n < 4; ++n) {
        const int row = wc * 64 + n * 16 + (lane & 15);
        const int ch  = (ks * 4 + (lane >> 4)) ^ (row & 7);
        bf[n] = *(const s16x8*)((const char*)Bl + row * 128 + ch * 16);
      }
#pragma unroll
      for (int m = 0; m < 4; ++m)
#pragma unroll
        for (int n = 0; n < 4; ++n)
          acc[m][n] = __builtin_amdgcn_mfma_f32_16x16x32_bf16(af[m], bf[n], acc[m][n], 0, 0, 0);
    }
    __syncthreads();
  }

  const int g = lane >> 4;

  // fast path: write s^T tile as fp8 e4m3 (4B per fragment; min from fp32 acc below)
  if (PASS == 2) {
#pragma unroll
    for (int m = 0; m < 4; ++m) {
#pragma unroll
      for (int n = 0; n < 4; ++n) {
        const int c = jt * 128 + wc * 64 + n * 16 + (lane & 15);  // global Y index
        const int r = it * 128 + wr * 64 + m * 16 + g * 4;        // global X index
        int pk = __builtin_amdgcn_cvt_pk_fp8_f32(acc[m][n][0], acc[m][n][1], 0, false);
        pk     = __builtin_amdgcn_cvt_pk_fp8_f32(acc[m][n][2], acc[m][n][3], pk, true);
        *(unsigned int*)(sT + ((size_t)b * N_ + c) * N_ + r) = (unsigned int)pk;
      }
    }
  }

  // per-row (over this block's 128 cols) min or sum(exp)
#pragma unroll
  for (int m = 0; m < 4; ++m) {
#pragma unroll
    for (int j = 0; j < 4; ++j) {
      const int r = wr * 64 + m * 16 + g * 4 + j;   // local output row
      float v;
      if (PASS != 1) {
        v = 1e30f;
#pragma unroll
        for (int n = 0; n < 4; ++n) {
          float d = fmaxf(1.0f - acc[m][n][j], 0.0f);
          v = fminf(v, d);
        }
#pragma unroll
        for (int off = 1; off < 16; off <<= 1) v = fminf(v, __shfl_xor(v, off));
      } else {
        const float mv  = minf[(size_t)b * N_ + it * 128 + r];
        const float inv = 10.0f / (mv + 1e-5f);
        v = 0.f;
#pragma unroll
        for (int n = 0; n < 4; ++n) {
          float d = fmaxf(1.0f - acc[m][n][j], 0.0f);
          v += __expf(10.0f - d * inv);
        }
#pragma unroll
        for (int off = 1; off < 16; off <<= 1) v += __shfl_xor(v, off);
      }
      if ((lane & 15) == 0) lred[wc][r] = v;
    }
  }
  __syncthreads();
  if (t < 128) {
    const float a = lred[0][t], c = lred[1][t];
    pout[(size_t)jt * (B_ * N_) + b * N_ + it * 128 + t] = (PASS == 1) ? (a + c) : fminf(a, c);
  }
}

// ---------- fold 32 j-tile partial mins ----------
__global__ void k_minred(const float* __restrict__ pmin, float* __restrict__ minf) {
  const int r = blockIdx.x * 256 + threadIdx.x;   // 16384 rows
  float v = 1e30f;
#pragma unroll 4
  for (int i = 0; i < 32; ++i) v = fminf(v, pmin[(size_t)i * (B_ * N_) + r]);
  minf[r] = v;
}

// ---------- streaming sum-exp over materialized fp8 s^T ----------
// grid = B_*2*NPJ ; each block: 2048 rows (8/thread) x (4096/NPJ) cols
__global__ void __launch_bounds__(256) k_sumexp(
    const unsigned char* __restrict__ sT, const float* __restrict__ minf,
    float* __restrict__ psum) {
  const int bid = blockIdx.x;
  const int b  = bid / (2 * NPJ);
  const int rh = (bid / NPJ) & 1;
  const int jc = bid % NPJ;
  const int t  = threadIdx.x;
  const int r0 = rh * 2048 + t * 8;
  const int CC = N_ / NPJ;  // 64 cols per block

  const unsigned char* base = sT + ((size_t)b * N_ + (size_t)jc * CC) * N_ + r0;

  float alpha[8], acc8[8];
#pragma unroll
  for (int i = 0; i < 8; ++i) {
    const float m = minf[b * N_ + r0 + i];
    alpha[i] = 10.0f / (m + 1e-5f);
    acc8[i] = 0.f;
  }

  for (int c = 0; c < CC; c += 2) {
    const uint2 u0 = *(const uint2*)(base + (size_t)(c    ) * N_);
    const uint2 u1 = *(const uint2*)(base + (size_t)(c + 1) * N_);
    float s0[8], s1[8];
#pragma unroll
    for (int h = 0; h < 2; ++h) {
      const unsigned int w0 = h ? u0.y : u0.x;
      const unsigned int w1 = h ? u1.y : u1.x;
      f32x2 a01 = __builtin_amdgcn_cvt_pk_f32_fp8((int)w0, false);
      f32x2 a23 = __builtin_amdgcn_cvt_pk_f32_fp8((int)w0, true);
      f32x2 b01 = __builtin_amdgcn_cvt_pk_f32_fp8((int)w1, false);
      f32x2 b23 = __builtin_amdgcn_cvt_pk_f32_fp8((int)w1, true);
      s0[h * 4 + 0] = a01[0]; s0[h * 4 + 1] = a01[1];
      s0[h * 4 + 2] = a23[0]; s0[h * 4 + 3] = a23[1];
      s1[h * 4 + 0] = b01[0]; s1[h * 4 + 1] = b01[1];
      s1[h * 4 + 2] = b23[0]; s1[h * 4 + 3] = b23[1];
    }
#pragma unroll
    for (int i = 0; i < 8; ++i) {
      const float d0 = fmaxf(1.0f - s0[i], 0.0f);
      const float d1 = fmaxf(1.0f - s1[i], 0.0f);
      acc8[i] += __expf(10.0f - d0 * alpha[i]) + __expf(10.0f - d1 * alpha[i]);
    }
  }
  float* out = psum + (size_t)jc * (B_ * N_) + b * N_ + r0;
#pragma unroll
  for (int i = 0; i < 8; ++i) out[i] = acc8[i];
}

// ---------- per-row contribution: exp((1-m/(m+1e-5))/h) / S ----------
template <int NP>
__global__ void k_contrib(const float* __restrict__ psum, const float* __restrict__ minf,
                          float* __restrict__ contrib) {
  const int r = blockIdx.x * 256 + threadIdx.x;
  float s = 0.f;
#pragma unroll 4
  for (int i = 0; i < NP; ++i) s += psum[(size_t)i * (B_ * N_) + r];
  const float m = minf[r];
  const float num = __expf(10.0f - 10.0f * m / (m + 1e-5f));
  contrib[r] = num / s;
}

// ---------- final loss ----------
__global__ void k_loss(const float* __restrict__ contrib, float* __restrict__ out) {
  const int t = threadIdx.x;    // 256
  __shared__ float sw_[4];
  float loss = 0.f;
  for (int b = 0; b < B_; ++b) {
    float s = 0.f;
    for (int i = t; i < N_; i += 256) s += contrib[b * N_ + i];
#pragma unroll
    for (int off = 32; off; off >>= 1) s += __shfl_down(s, off);
    if ((t & 63) == 0) sw_[t >> 6] = s;
    __syncthreads();
    if (t == 0) {
      const float cx = (sw_[0] + sw_[1] + sw_[2] + sw_[3]) * (1.0f / (float)N_);
      loss += -logf(cx);
    }
    __syncthreads();
  }
  if (t == 0) out[0] = loss * (1.0f / (float)B_);
}

extern "C" void kernel_launch(void* const* d_in, const int* in_sizes, int n_in,
                              void* d_out, int out_size, void* d_ws, size_t ws_size,
                              hipStream_t stream) {
  const float* X = (const float*)d_in[0];
  const float* Y = (const float*)d_in[1];
  float* out = (float*)d_out;

  char* w = (char*)d_ws;
  size_t off = 0;
  float*          mu   = (float*)(w + off);  off += 4096;
  unsigned short* Xn   = (unsigned short*)(w + off);  off += 8388608;
  unsigned short* Yn   = (unsigned short*)(w + off);  off += 8388608;
  float*          pmin = (float*)(w + off);  off += 2097152;              // 32 partials
  float*          psum = (float*)(w + off);  off += (size_t)NPJ * B_ * N_ * 4;  // 4 MB
  float*          minf = (float*)(w + off);  off += 65536;
  float*          ctr  = (float*)(w + off);  off += 65536;
  unsigned char*  sT   = (unsigned char*)(w + off);
  const size_t need = off + (size_t)B_ * N_ * N_;   // ~84 MB (fp8)

  k_mu   <<<B_ * C_,  256, 0, stream>>>(Y, mu);
  k_norm <<<B_ * 128, 256, 0, stream>>>(X, Y, mu, Xn, Yn);

  if (ws_size >= need) {
    // fast path: one GEMM materializes fp8 s^T + row-min partials, then sum-exp
    k_gemm<2><<<B_ * NT * NT, 256, 0, stream>>>(Xn, Yn, pmin, nullptr, sT);
    k_minred<<<B_ * N_ / 256, 256, 0, stream>>>(pmin, minf);
    k_sumexp<<<B_ * 2 * NPJ,  256, 0, stream>>>(sT, minf, psum);
    k_contrib<NPJ><<<B_ * N_ / 256, 256, 0, stream>>>(psum, minf, ctr);
  } else {
    // fallback: two GEMM passes
    k_gemm<0><<<B_ * NT * NT, 256, 0, stream>>>(Xn, Yn, pmin, nullptr, nullptr);
    k_minred<<<B_ * N_ / 256, 256, 0, stream>>>(pmin, minf);
    k_gemm<1><<<B_ * NT * NT, 256, 0, stream>>>(Xn, Yn, psum, minf, nullptr);
    k_contrib<32><<<B_ * N_ / 256, 256, 0, stream>>>(psum, minf, ctr);
  }
  k_loss <<<1, 256, 0, stream>>>(ctr, out);

  (void)in_sizes; (void)n_in; (void)out_size; (void)ws_size;
}